// Round 3
// baseline (63.872 us; speedup 1.0000x reference)
//
#include <hip/hip_runtime.h>

#define TILE    16
#define BLOCK   256
#define EMBED   128
#define VOCAB   50257
#define ESTRIDE 132           // 128 + 4 pad floats (16B-aligned rows, bank spread)
#define NGROUPS (BLOCK / 16)  // 16 groups of 16 lanes

// 16-lane group per (token, path-node). fc row read coalesced (256B per group
// per inst), dot = 8 in-lane FMA + 4-step shfl_xor reduce. Path metadata is
// pre-staged in LDS as int2{row, code_or_-1}; loads are branchless so the
// 2-way unrolled loop pipelines.
__global__ __launch_bounds__(BLOCK) void hs_main(
    const float* __restrict__ emb,        // [T, 128]
    const int*   __restrict__ target,     // [T]
    const float* __restrict__ fc,         // [V-1, 128]
    const int*   __restrict__ path_idx,   // [V, D]
    const float* __restrict__ path_code,  // [V, D]
    const float* __restrict__ path_mask,  // [V, D]
    int T, int D,
    float* __restrict__ partial_b,        // [gridDim.x]
    float* __restrict__ partial_c)        // [gridDim.x]
{
    extern __shared__ char smem[];
    float* se  = (float*)smem;                          // [TILE*ESTRIDE]
    int2*  sic = (int2*)(smem + TILE * ESTRIDE * 4);    // [TILE*D], tk-major
    __shared__ float sb[BLOCK / 64];
    __shared__ float sc[BLOCK / 64];

    const int tok0 = blockIdx.x * TILE;
    const int ntok = min(TILE, T - tok0);

    // Stage emb tile (zero-fill rows past ntok so padded dots stay finite).
    const float4* g4 = (const float4*)(emb + (size_t)tok0 * EMBED);
    for (int j = threadIdx.x; j < TILE * (EMBED / 4); j += BLOCK) {
        const int f = j * 4, tk = f >> 7, kk = f & 127;
        float4 v = make_float4(0.f, 0.f, 0.f, 0.f);
        if (tk < ntok) v = g4[j];
        *(float4*)&se[tk * ESTRIDE + kk] = v;
    }
    // Stage path meta: sic[tk*D+d] = {row, code} or {0, -1} for padded/invalid.
    for (int j = threadIdx.x; j < TILE * D; j += BLOCK) {
        const int tk = j / D, d = j - tk * D;
        int2 m = make_int2(0, __float_as_int(-1.0f));
        if (tk < ntok) {
            const int v = target[tok0 + tk];
            const size_t po = (size_t)v * D + d;
            if (path_mask[po] != 0.f)
                m = make_int2(path_idx[po], __float_as_int(path_code[po]));
        }
        sic[j] = m;
    }
    __syncthreads();

    const int group = threadIdx.x >> 4;
    const int sub   = threadIdx.x & 15;
    const int items = TILE * D;

    float accb = 0.f, accc = 0.f;

    for (int it = group; it < items; it += 2 * NGROUPS) {
        const int it2 = it + NGROUPS;
        const int tk1 = it & (TILE - 1), d1 = it >> 4;
        int2 m1 = sic[tk1 * D + d1];
        int tk2 = it2 & (TILE - 1), d2 = it2 >> 4;
        int2 m2 = make_int2(0, __float_as_int(-1.0f));
        if (it2 < items) m2 = sic[tk2 * D + d2];

        // fc rows: 16 lanes x float4[sub], float4[sub+16] -> 2x256B coalesced
        const float4* w1 = (const float4*)(fc + (size_t)m1.x * EMBED);
        const float4* w2 = (const float4*)(fc + (size_t)m2.x * EMBED);
        const float4 w1a = w1[sub], w1b = w1[sub + 16];
        const float4 w2a = w2[sub], w2b = w2[sub + 16];

        const float4* e1 = (const float4*)&se[tk1 * ESTRIDE];
        const float4* e2 = (const float4*)&se[tk2 * ESTRIDE];
        const float4 e1a = e1[sub], e1b = e1[sub + 16];
        const float4 e2a = e2[sub], e2b = e2[sub + 16];

        float dp1 = 0.f, dp2 = 0.f;
        dp1 = fmaf(e1a.x, w1a.x, dp1); dp1 = fmaf(e1a.y, w1a.y, dp1);
        dp1 = fmaf(e1a.z, w1a.z, dp1); dp1 = fmaf(e1a.w, w1a.w, dp1);
        dp1 = fmaf(e1b.x, w1b.x, dp1); dp1 = fmaf(e1b.y, w1b.y, dp1);
        dp1 = fmaf(e1b.z, w1b.z, dp1); dp1 = fmaf(e1b.w, w1b.w, dp1);
        dp2 = fmaf(e2a.x, w2a.x, dp2); dp2 = fmaf(e2a.y, w2a.y, dp2);
        dp2 = fmaf(e2a.z, w2a.z, dp2); dp2 = fmaf(e2a.w, w2a.w, dp2);
        dp2 = fmaf(e2b.x, w2b.x, dp2); dp2 = fmaf(e2b.y, w2b.y, dp2);
        dp2 = fmaf(e2b.z, w2b.z, dp2); dp2 = fmaf(e2b.w, w2b.w, dp2);

        // reduce within the 16-lane group
        #pragma unroll
        for (int o = 1; o < 16; o <<= 1) {
            dp1 += __shfl_xor(dp1, o);
            dp2 += __shfl_xor(dp2, o);
        }

        const float cy1 = __int_as_float(m1.y);
        const float wg1 = cy1 >= 0.f ? 1.f : 0.f;
        const float cd1 = fmaxf(cy1, 0.f);
        accb += wg1 * (fmaxf(dp1, 0.f) - dp1 * cd1 + log1pf(expf(-fabsf(dp1))));
        accc += wg1;

        const float cy2 = __int_as_float(m2.y);
        const float wg2 = cy2 >= 0.f ? 1.f : 0.f;
        const float cd2 = fmaxf(cy2, 0.f);
        accb += wg2 * (fmaxf(dp2, 0.f) - dp2 * cd2 + log1pf(expf(-fabsf(dp2))));
        accc += wg2;
    }

    // Every lane of a group holds the same contribution (16x overcount) in
    // BOTH numerator and denominator -> the final ratio is unchanged.
    #pragma unroll
    for (int o = 32; o > 0; o >>= 1) {
        accb += __shfl_xor(accb, o);
        accc += __shfl_xor(accc, o);
    }
    const int wave = threadIdx.x >> 6;
    const int lane = threadIdx.x & 63;
    if (lane == 0) { sb[wave] = accb; sc[wave] = accc; }
    __syncthreads();
    if (threadIdx.x == 0) {
        float b = 0.f, c = 0.f;
        #pragma unroll
        for (int i = 0; i < BLOCK / 64; ++i) { b += sb[i]; c += sc[i]; }
        partial_b[blockIdx.x] = b;
        partial_c[blockIdx.x] = c;
    }
}

// Deterministic single-block finalize: double-precision sums, then divide.
__global__ __launch_bounds__(256) void hs_finalize(
    const float* __restrict__ pb,
    const float* __restrict__ pc,
    int n, float* __restrict__ out)
{
    __shared__ double rb[256];
    __shared__ double rc[256];

    double sbv = 0.0, scv = 0.0;
    for (int i = threadIdx.x; i < n; i += 256) {
        sbv += (double)pb[i];
        scv += (double)pc[i];
    }
    rb[threadIdx.x] = sbv;
    rc[threadIdx.x] = scv;
    __syncthreads();

    for (int s = 128; s > 0; s >>= 1) {
        if (threadIdx.x < s) {
            rb[threadIdx.x] += rb[threadIdx.x + s];
            rc[threadIdx.x] += rc[threadIdx.x + s];
        }
        __syncthreads();
    }
    if (threadIdx.x == 0) out[0] = (float)(rb[0] / rc[0]);
}

extern "C" void kernel_launch(void* const* d_in, const int* in_sizes, int n_in,
                              void* d_out, int out_size, void* d_ws, size_t ws_size,
                              hipStream_t stream) {
    const float* emb   = (const float*)d_in[0];
    const int*   tgt   = (const int*)  d_in[1];
    const float* fc    = (const float*)d_in[2];
    const int*   pidx  = (const int*)  d_in[3];
    const float* pcode = (const float*)d_in[4];
    const float* pmask = (const float*)d_in[5];

    const int T = in_sizes[1];            // 32768 tokens
    const int D = in_sizes[3] / VOCAB;    // padded max path depth

    const int nblocks = (T + TILE - 1) / TILE;   // 2048
    const size_t shmem = (size_t)TILE * ESTRIDE * 4 + (size_t)TILE * D * 8;

    float* pb = (float*)d_ws;
    float* pc = pb + nblocks;
    float* out = (float*)d_out;

    hs_main<<<nblocks, BLOCK, shmem, stream>>>(
        emb, tgt, fc, pidx, pcode, pmask, T, D, pb, pc);
    hs_finalize<<<1, 256, 0, stream>>>(pb, pc, nblocks, out);
}

// Round 4
// 48.980 us; speedup vs baseline: 1.3040x; 1.3040x over previous
//
#include <hip/hip_runtime.h>

#define TILE    16
#define BLOCK   256
#define EMBED   128
#define VOCAB   50257
#define ESTRIDE 132   // 128 + 4 pad floats: 16B-aligned rows, spreads banks

// Thread-per-(token, path-node) item, d-major: a wave's 64 lanes cover 16
// tokens x 4 consecutive depths, so low-depth waves gather the same hot fc
// rows (L1 broadcast). emb tile + path meta staged in LDS once per block.
// BCE computed once per item (amortized 64x per wave-instruction).
__global__ __launch_bounds__(BLOCK) void hs_main(
    const float* __restrict__ emb,        // [T, 128]
    const int*   __restrict__ target,     // [T]
    const float* __restrict__ fc,         // [V-1, 128]
    const int*   __restrict__ path_idx,   // [V, D]
    const float* __restrict__ path_code,  // [V, D]
    const float* __restrict__ path_mask,  // [V, D]
    int T, int D,
    float* __restrict__ partial_b,        // [gridDim.x]
    float* __restrict__ partial_c)        // [gridDim.x]
{
    extern __shared__ char smem[];
    float* se  = (float*)smem;                          // [TILE*ESTRIDE]
    int2*  sic = (int2*)(smem + TILE * ESTRIDE * 4);    // [TILE*D], tk-major
    __shared__ float sb[BLOCK / 64];
    __shared__ float sc[BLOCK / 64];

    const int tok0 = blockIdx.x * TILE;
    const int ntok = min(TILE, T - tok0);

    // Stage emb tile into padded LDS (zero-fill past ntok).
    const float4* g4 = (const float4*)(emb + (size_t)tok0 * EMBED);
    for (int j = threadIdx.x; j < TILE * (EMBED / 4); j += BLOCK) {
        const int f = j * 4, tk = f >> 7, kk = f & 127;
        float4 v = make_float4(0.f, 0.f, 0.f, 0.f);
        if (tk < ntok) v = g4[j];
        *(float4*)&se[tk * ESTRIDE + kk] = v;
    }
    // Stage path meta tk-major (coalesced over d within each token segment):
    // sic[tk*D+d] = {row, code} or {0, -1} for padded/invalid slots.
    for (int j = threadIdx.x; j < TILE * D; j += BLOCK) {
        const int tk = j / D, d = j - tk * D;
        int2 m = make_int2(0, __float_as_int(-1.0f));
        if (tk < ntok) {
            const int v = target[tok0 + tk];
            const size_t po = (size_t)v * D + d;
            if (path_mask[po] != 0.f)
                m = make_int2(path_idx[po], __float_as_int(path_code[po]));
        }
        sic[j] = m;
    }
    __syncthreads();

    float accb = 0.f, accc = 0.f;

    const int items = TILE * D;
    for (int it = threadIdx.x; it < items; it += BLOCK) {
        const int tk = it & (TILE - 1);   // item = d*TILE + tk (d-major)
        const int d  = it >> 4;
        const int2 m = sic[tk * D + d];
        const float code = __int_as_float(m.y);
        if (code >= 0.f) {                // valid (mask) item
            const float4* w4 = (const float4*)(fc + (size_t)m.x * EMBED);
            const float4* e4 = (const float4*)&se[tk * ESTRIDE];
            float s0 = 0.f, s1 = 0.f, s2 = 0.f, s3 = 0.f;
            #pragma unroll 8
            for (int k = 0; k < EMBED / 4; ++k) {
                const float4 w  = w4[k];
                const float4 ev = e4[k];
                s0 = fmaf(ev.x, w.x, s0);
                s1 = fmaf(ev.y, w.y, s1);
                s2 = fmaf(ev.z, w.z, s2);
                s3 = fmaf(ev.w, w.w, s3);
            }
            const float x = (s0 + s1) + (s2 + s3);
            accb += fmaxf(x, 0.f) - x * code + log1pf(expf(-fabsf(x)));
            accc += 1.f;
        }
    }

    // One reduction per block.
    #pragma unroll
    for (int o = 32; o > 0; o >>= 1) {
        accb += __shfl_xor(accb, o);
        accc += __shfl_xor(accc, o);
    }
    const int wave = threadIdx.x >> 6;
    const int lane = threadIdx.x & 63;
    if (lane == 0) { sb[wave] = accb; sc[wave] = accc; }
    __syncthreads();
    if (threadIdx.x == 0) {
        float b = 0.f, c = 0.f;
        #pragma unroll
        for (int i = 0; i < BLOCK / 64; ++i) { b += sb[i]; c += sc[i]; }
        partial_b[blockIdx.x] = b;
        partial_c[blockIdx.x] = c;
    }
}

// Deterministic single-block finalize: double-precision sums, then divide.
__global__ __launch_bounds__(256) void hs_finalize(
    const float* __restrict__ pb,
    const float* __restrict__ pc,
    int n, float* __restrict__ out)
{
    __shared__ double rb[256];
    __shared__ double rc[256];

    double sbv = 0.0, scv = 0.0;
    for (int i = threadIdx.x; i < n; i += 256) {
        sbv += (double)pb[i];
        scv += (double)pc[i];
    }
    rb[threadIdx.x] = sbv;
    rc[threadIdx.x] = scv;
    __syncthreads();

    for (int s = 128; s > 0; s >>= 1) {
        if (threadIdx.x < s) {
            rb[threadIdx.x] += rb[threadIdx.x + s];
            rc[threadIdx.x] += rc[threadIdx.x + s];
        }
        __syncthreads();
    }
    if (threadIdx.x == 0) out[0] = (float)(rb[0] / rc[0]);
}

extern "C" void kernel_launch(void* const* d_in, const int* in_sizes, int n_in,
                              void* d_out, int out_size, void* d_ws, size_t ws_size,
                              hipStream_t stream) {
    const float* emb   = (const float*)d_in[0];
    const int*   tgt   = (const int*)  d_in[1];
    const float* fc    = (const float*)d_in[2];
    const int*   pidx  = (const int*)  d_in[3];
    const float* pcode = (const float*)d_in[4];
    const float* pmask = (const float*)d_in[5];

    const int T = in_sizes[1];            // 32768 tokens
    const int D = in_sizes[3] / VOCAB;    // padded max path depth

    const int nblocks = (T + TILE - 1) / TILE;   // 2048
    const size_t shmem = (size_t)TILE * ESTRIDE * 4 + (size_t)TILE * D * 8;

    float* pb = (float*)d_ws;
    float* pc = pb + nblocks;
    float* out = (float*)d_out;

    hs_main<<<nblocks, BLOCK, shmem, stream>>>(
        emb, tgt, fc, pidx, pcode, pmask, T, D, pb, pc);
    hs_finalize<<<1, 256, 0, stream>>>(pb, pc, nblocks, out);
}

// Round 5
// 31.902 us; speedup vs baseline: 2.0021x; 1.5353x over previous
//
#include <hip/hip_runtime.h>

#define TILE    16
#define BLOCK   256
#define EMBED   128
#define VOCAB   50257
#define ESTRIDE 132   // 4*odd floats: spreads rows across bank-groups

// 4-lane group per (token, path-node) item. The 4 lanes read ADJACENT float4s
// of the fc row (k*4+sub), so each load instruction's quad consumes whole 64B
// lines: 16 lines/instr instead of 64 (the round-2/4 TA bottleneck), and each
// row's 8 lines are fetched exactly once. Within a wave-iteration all 16
// groups process the same depth d (tk = g), so shallow depths hit the same
// hot fc row (L1 broadcast). Dot = 32 in-lane FMA + 2-step intra-quad shuffle.
__global__ __launch_bounds__(BLOCK) void hs_main(
    const float* __restrict__ emb,        // [T, 128]
    const int*   __restrict__ target,     // [T]
    const float* __restrict__ fc,         // [V-1, 128]
    const int*   __restrict__ path_idx,   // [V, D]
    const float* __restrict__ path_code,  // [V, D]
    const float* __restrict__ path_mask,  // [V, D]
    int T, int D,
    float* __restrict__ partial_b,        // [gridDim.x]
    float* __restrict__ partial_c)        // [gridDim.x]
{
    extern __shared__ char smem[];
    float* se  = (float*)smem;                          // [TILE*ESTRIDE]
    int2*  sic = (int2*)(smem + TILE * ESTRIDE * 4);    // [TILE*D], d-major
    __shared__ float sb[BLOCK / 64];
    __shared__ float sc[BLOCK / 64];

    const int tok0 = blockIdx.x * TILE;
    const int ntok = min(TILE, T - tok0);

    // Stage emb tile into padded LDS (zero-fill past ntok).
    const float4* g4 = (const float4*)(emb + (size_t)tok0 * EMBED);
    for (int j = threadIdx.x; j < TILE * (EMBED / 4); j += BLOCK) {
        const int f = j * 4, tk = f >> 7, kk = f & 127;
        float4 v = make_float4(0.f, 0.f, 0.f, 0.f);
        if (tk < ntok) v = g4[j];
        *(float4*)&se[tk * ESTRIDE + kk] = v;
    }
    // Stage path meta D-MAJOR: sic[d*TILE+tk] = {row, code} or {0,-1}.
    for (int j = threadIdx.x; j < TILE * D; j += BLOCK) {
        const int tk = j & (TILE - 1), d = j >> 4;
        int2 m = make_int2(0, __float_as_int(-1.0f));
        if (tk < ntok) {
            const int v = target[tok0 + tk];
            const size_t po = (size_t)v * D + d;
            if (path_mask[po] != 0.f)
                m = make_int2(path_idx[po], __float_as_int(path_code[po]));
        }
        sic[j] = m;
    }
    __syncthreads();

    const int wave = threadIdx.x >> 6;
    const int g    = (threadIdx.x >> 2) & 15;   // group id = token tk
    const int sub  = threadIdx.x & 3;           // quad sub-lane

    float accb = 0.f, accc = 0.f;

    const int items = TILE * D;
    for (int it = wave * 16; it < items; it += 64) {
        const int item = it + g;                // d = it>>4 (wave-uniform), tk = g
        const int2 m = sic[item];
        const float code = __int_as_float(m.y);
        if (code >= 0.f) {                      // whole quad shares validity
            const float4* w4 = (const float4*)(fc + (size_t)m.x * EMBED);
            const float4* e4 = (const float4*)&se[g * ESTRIDE];
            float s0 = 0.f, s1 = 0.f, s2 = 0.f, s3 = 0.f;
            #pragma unroll
            for (int k = 0; k < 8; ++k) {
                const float4 w  = w4[k * 4 + sub];
                const float4 ev = e4[k * 4 + sub];
                s0 = fmaf(ev.x, w.x, s0);
                s1 = fmaf(ev.y, w.y, s1);
                s2 = fmaf(ev.z, w.z, s2);
                s3 = fmaf(ev.w, w.w, s3);
            }
            float x = (s0 + s1) + (s2 + s3);
            x += __shfl_xor(x, 1);              // reduce across the quad
            x += __shfl_xor(x, 2);
            // fast stable BCE (hw exp/log; threshold is 5.4e-2 -> plenty)
            accb += fmaxf(x, 0.f) - x * code + __logf(1.f + __expf(-fabsf(x)));
            accc += 1.f;                        // 4x overcount cancels in ratio
        }
    }

    // One reduction per block.
    #pragma unroll
    for (int o = 32; o > 0; o >>= 1) {
        accb += __shfl_xor(accb, o);
        accc += __shfl_xor(accc, o);
    }
    const int lane = threadIdx.x & 63;
    if (lane == 0) { sb[wave] = accb; sc[wave] = accc; }
    __syncthreads();
    if (threadIdx.x == 0) {
        float b = 0.f, c = 0.f;
        #pragma unroll
        for (int i = 0; i < BLOCK / 64; ++i) { b += sb[i]; c += sc[i]; }
        partial_b[blockIdx.x] = b;
        partial_c[blockIdx.x] = c;
    }
}

// Deterministic single-block finalize: double-precision sums, then divide.
__global__ __launch_bounds__(256) void hs_finalize(
    const float* __restrict__ pb,
    const float* __restrict__ pc,
    int n, float* __restrict__ out)
{
    __shared__ double rb[256];
    __shared__ double rc[256];

    double sbv = 0.0, scv = 0.0;
    for (int i = threadIdx.x; i < n; i += 256) {
        sbv += (double)pb[i];
        scv += (double)pc[i];
    }
    rb[threadIdx.x] = sbv;
    rc[threadIdx.x] = scv;
    __syncthreads();

    for (int s = 128; s > 0; s >>= 1) {
        if (threadIdx.x < s) {
            rb[threadIdx.x] += rb[threadIdx.x + s];
            rc[threadIdx.x] += rc[threadIdx.x + s];
        }
        __syncthreads();
    }
    if (threadIdx.x == 0) out[0] = (float)(rb[0] / rc[0]);
}

extern "C" void kernel_launch(void* const* d_in, const int* in_sizes, int n_in,
                              void* d_out, int out_size, void* d_ws, size_t ws_size,
                              hipStream_t stream) {
    const float* emb   = (const float*)d_in[0];
    const int*   tgt   = (const int*)  d_in[1];
    const float* fc    = (const float*)d_in[2];
    const int*   pidx  = (const int*)  d_in[3];
    const float* pcode = (const float*)d_in[4];
    const float* pmask = (const float*)d_in[5];

    const int T = in_sizes[1];            // 32768 tokens
    const int D = in_sizes[3] / VOCAB;    // padded max path depth

    const int nblocks = (T + TILE - 1) / TILE;   // 2048
    const size_t shmem = (size_t)TILE * ESTRIDE * 4 + (size_t)TILE * D * 8;

    float* pb = (float*)d_ws;
    float* pc = pb + nblocks;
    float* out = (float*)d_out;

    hs_main<<<nblocks, BLOCK, shmem, stream>>>(
        emb, tgt, fc, pidx, pcode, pmask, T, D, pb, pc);
    hs_finalize<<<1, 256, 0, stream>>>(pb, pc, nblocks, out);
}